// Round 17
// baseline (210.285 us; speedup 1.0000x reference)
//
#include <hip/hip_runtime.h>
#include <hip/hip_bf16.h>

// MPNN layer: edge MLP (32x32x16 MFMA, LDS weights, 32-row waves) ->
// CSR scatter-sum -> LN -> fused dense MLP (3 GEMMs, 16x16) + LN2.
// N=10000, E=160000, H=128, NIN=128, DD=256 (sizes derived at runtime).

typedef __attribute__((ext_vector_type(8))) short bf16x8;
typedef __attribute__((ext_vector_type(4))) float f32x4;
typedef __attribute__((ext_vector_type(16))) float f32x16;

__device__ __forceinline__ unsigned short f2bf(float f) {
  union { float f; unsigned u; } v; v.f = f;
  return (unsigned short)((v.u + 0x7fffu + ((v.u >> 16) & 1u)) >> 16);
}
__device__ __forceinline__ unsigned pk2bf(float a, float b) {
  __hip_bfloat162 h = __float22bfloat162_rn(make_float2(a, b));  // v_cvt_pk_bf16_f32
  union { __hip_bfloat162 h; unsigned u; } v; v.h = h;
  return v.u;
}
__device__ __forceinline__ unsigned short bf1(float x) {
  return (unsigned short)pk2bf(x, x);
}
__device__ __forceinline__ float bf2f(unsigned s) {
  union { unsigned u; float f; } v; v.u = s << 16;
  return v.f;
}
// gelu tanh-form, ~10 VALU ops, |err| <= ~3e-4
__device__ __forceinline__ float gelu_f(float x) {
  float x2 = x * x;
  float u2 = x * fmaf(0.0713548162f, x2, 1.5957691216f);
  float e = __expf(u2);
  float r = __builtin_amdgcn_rcpf(e + 1.0f);
  float th = fmaf(-2.0f, r, 1.0f);
  float hx = 0.5f * x;
  return fmaf(hx, th, hx);
}

// ---------------- weight packing (+ zero counts) ----------------
// pw0/pw1 (32x32x16 B layout): frag[j] = B[k=kstep*16+(lane>>5)*8+j][ct*32+(lane&31)]
//   pw0: K=256 -> 64 groups (ct*16+kstep); pw1: K=128 -> 32 groups (ct*8+kstep)
// pd* (16x16x32 B layout, unchanged): b[j]=B[ks*32+(lane>>4)*8+j][w*WC+ct*16+(lane&15)]
__global__ void k_pack(const float* __restrict__ mw0, const float* __restrict__ mw1,
                       const float* __restrict__ dw0, const float* __restrict__ dw1,
                       const float* __restrict__ dw2,
                       unsigned short* __restrict__ pw0, unsigned short* __restrict__ pw1,
                       unsigned short* __restrict__ pd0, unsigned short* __restrict__ pd1,
                       unsigned short* __restrict__ pd2,
                       int* __restrict__ counts, int Nn) {
  int g = blockIdx.x, lane = threadIdx.x;
  int z = g * 64 + lane;
  if (z < Nn) counts[z] = 0;
  unsigned short o[8];
  if (g < 96) {
    // edge weights: 32-col MFMA layout
    const float* src; unsigned short* dst; int lg;
    int ct, kstep;
    if (g < 64) { src = mw0; dst = pw0; lg = g; ct = lg >> 4; kstep = lg & 15; }
    else        { src = mw1; dst = pw1; lg = g - 64; ct = lg >> 3; kstep = lg & 7; }
    int col = ct * 32 + (lane & 31);
    int k0 = kstep * 16 + (lane >> 5) * 8;
#pragma unroll
    for (int j = 0; j < 8; ++j) o[j] = f2bf(src[(size_t)(k0 + j) * 128 + col]);
    uint4 u;
    u.x = (unsigned)o[0] | ((unsigned)o[1] << 16);
    u.y = (unsigned)o[2] | ((unsigned)o[3] << 16);
    u.z = (unsigned)o[4] | ((unsigned)o[5] << 16);
    u.w = (unsigned)o[6] | ((unsigned)o[7] << 16);
    *(uint4*)(dst + (size_t)(lg * 64 + lane) * 8) = u;
    return;
  }
  const float* src; unsigned short* dst; int K, N, WC, base;
  if (g < 160)      { src = dw0; dst = pd0; K = 128; N = 256; WC = 64; base = 96; }
  else if (g < 288) { src = dw1; dst = pd1; K = 256; N = 256; WC = 64; base = 160; }
  else              { src = dw2; dst = pd2; K = 256; N = 128; WC = 32; base = 288; }
  int lg = g - base;
  int KS = K >> 5, CTKS = (WC >> 4) * KS;
  int w = lg / CTKS, rem = lg % CTKS, ct = rem / KS, ks = rem % KS;
  int col = w * WC + ct * 16 + (lane & 15);
  int k0 = ks * 32 + (lane >> 4) * 8;
#pragma unroll
  for (int j = 0; j < 8; ++j) o[j] = f2bf(src[(size_t)(k0 + j) * N + col]);
  uint4 u;
  u.x = (unsigned)o[0] | ((unsigned)o[1] << 16);
  u.y = (unsigned)o[2] | ((unsigned)o[3] << 16);
  u.z = (unsigned)o[4] | ((unsigned)o[5] << 16);
  u.w = (unsigned)o[6] | ((unsigned)o[7] << 16);
  *(uint4*)(dst + (size_t)(lg * 64 + lane) * 8) = u;
}

// ---------------- CSR build ----------------
__global__ void k_hist(const int* __restrict__ eidx, int* __restrict__ counts, int E) {
  int e = blockIdx.x * 256 + threadIdx.x;
  if (e < E) atomicAdd(&counts[eidx[e]], 1);
}

__global__ __launch_bounds__(1024) void k_scan(const int* __restrict__ counts,
                                               int* __restrict__ row_start,
                                               int* __restrict__ cursor, int Nn) {
  __shared__ int sm[1024];
  int t = threadIdx.x;
  int chunk = (Nn + 1023) / 1024;
  int lo = t * chunk, hi = lo + chunk;
  if (hi > Nn) hi = Nn;
  int s = 0;
  for (int i = lo; i < hi; ++i) s += counts[i];
  sm[t] = s;
  __syncthreads();
  for (int o = 1; o < 1024; o <<= 1) {
    int u = (t >= o) ? sm[t - o] : 0;
    __syncthreads();
    sm[t] += u;
    __syncthreads();
  }
  int run = sm[t] - s;  // exclusive prefix
  for (int i = lo; i < hi; ++i) {
    row_start[i] = run; cursor[i] = run; run += counts[i];
  }
  if (t == 1023) row_start[Nn] = sm[1023];
}

__global__ void k_scatter(const int* __restrict__ eidx, int* __restrict__ cursor,
                          int* __restrict__ eorder, int E) {
  int e = blockIdx.x * 256 + threadIdx.x;
  if (e < E) {
    int pos = atomicAdd(&cursor[eidx[e]], 1);
    eorder[pos] = e;
  }
}

// ---------------- fused edge MLP: h_msg = gelu(gelu(hE@W0+b0)@W1+b1) ----------------
// 256 persistent blocks x 8 waves, (512,2). LDS = 160KB: 64K W0 | 32K W1 | 8x8K H.
// 32x32x16 MFMAs: wave owns 32 rows x 128 cols. K processed in two halves so
// A-loads overlap MFMAs. B fragments batched 4-deep; setprio around MFMAs;
// wave-private H bounce (32x32 C layout -> row-major) ; direct u16 stores.
__global__ __launch_bounds__(512, 2) void k_edge(
    const float* __restrict__ hE, const unsigned short* __restrict__ pw0,
    const unsigned short* __restrict__ pw1, const float* __restrict__ b0,
    const float* __restrict__ b1, unsigned short* __restrict__ hmsg, int E) {
  __shared__ __align__(16) char lds[163840];
  const int tid = threadIdx.x;  // 0..511
  const int wid = tid >> 6, lane = tid & 63;
  const int l31 = lane & 31, lsel = lane >> 5;
  char* Hw = lds + 98304 + wid * 8192;  // [32][256B] bf16, swizzled

  // stage weights: 96 KB = 6144 uint4 (512 threads x 12)
  {
    const uint4* s0 = (const uint4*)pw0;  // 4096 uint4
    const uint4* s1 = (const uint4*)pw1;  // 2048 uint4
    uint4* d = (uint4*)lds;
#pragma unroll
    for (int i = 0; i < 12; ++i) {
      int idx = i * 512 + tid;
      d[idx] = (idx < 4096) ? s0[idx] : s1[idx - 4096];
    }
  }
  float bb0[4], bb1[4];
#pragma unroll
  for (int ct = 0; ct < 4; ++ct) {
    bb0[ct] = b0[ct * 32 + l31];
    bb1[ct] = b1[ct * 32 + l31];
  }
  __syncthreads();  // weights visible; no barriers after this

  const int TILES = (E + 31) >> 5;
  const int WSLOTS = gridDim.x * 8;
  for (int t = blockIdx.x * 8 + wid; t < TILES; t += WSLOTS) {
    int rowA = t * 32 + l31; rowA = rowA < E ? rowA : E - 1;
    const float* ap = hE + (size_t)rowA * 256 + lsel * 8;

    // ---- load K-half 0 (ksteps 0..7) ----
    bf16x8 af[8];
    {
      f32x4 av[16];
#pragma unroll
      for (int kk = 0; kk < 8; ++kk) {
        av[2 * kk]     = *(const f32x4*)(ap + kk * 16);
        av[2 * kk + 1] = *(const f32x4*)(ap + kk * 16 + 4);
      }
#pragma unroll
      for (int kk = 0; kk < 8; ++kk) {
        union { unsigned u[4]; bf16x8 v; } pk;
        pk.u[0] = pk2bf(av[2 * kk][0], av[2 * kk][1]);
        pk.u[1] = pk2bf(av[2 * kk][2], av[2 * kk][3]);
        pk.u[2] = pk2bf(av[2 * kk + 1][0], av[2 * kk + 1][1]);
        pk.u[3] = pk2bf(av[2 * kk + 1][2], av[2 * kk + 1][3]);
        af[kk] = pk.v;
      }
    }
    // ---- issue K-half 1 loads (overlap with half-0 MFMAs) ----
    f32x4 av1[16];
#pragma unroll
    for (int kk = 0; kk < 8; ++kk) {
      av1[2 * kk]     = *(const f32x4*)(ap + 128 + kk * 16);
      av1[2 * kk + 1] = *(const f32x4*)(ap + 128 + kk * 16 + 4);
    }

    // GEMM1 half 0: ksteps 0..7
    f32x16 acc[4];
#pragma unroll
    for (int ct = 0; ct < 4; ++ct) {
      float b = bb0[ct];
#pragma unroll
      for (int q = 0; q < 16; ++q) acc[ct][q] = b;
    }
#pragma unroll
    for (int kk = 0; kk < 8; ++kk) {
      bf16x8 bfr[4];
#pragma unroll
      for (int ct = 0; ct < 4; ++ct)
        bfr[ct] = *(bf16x8*)(lds + (ct * 16 + kk) * 1024 + lane * 16);
      __builtin_amdgcn_s_setprio(1);
#pragma unroll
      for (int ct = 0; ct < 4; ++ct)
        acc[ct] = __builtin_amdgcn_mfma_f32_32x32x16_bf16(af[kk], bfr[ct], acc[ct], 0, 0, 0);
      __builtin_amdgcn_s_setprio(0);
    }
    // convert half 1 (WAR on af after half-0 MFMAs)
#pragma unroll
    for (int kk = 0; kk < 8; ++kk) {
      union { unsigned u[4]; bf16x8 v; } pk;
      pk.u[0] = pk2bf(av1[2 * kk][0], av1[2 * kk][1]);
      pk.u[1] = pk2bf(av1[2 * kk][2], av1[2 * kk][3]);
      pk.u[2] = pk2bf(av1[2 * kk + 1][0], av1[2 * kk + 1][1]);
      pk.u[3] = pk2bf(av1[2 * kk + 1][2], av1[2 * kk + 1][3]);
      af[kk] = pk.v;
    }
    // GEMM1 half 1: ksteps 8..15
#pragma unroll
    for (int kk = 0; kk < 8; ++kk) {
      bf16x8 bfr[4];
#pragma unroll
      for (int ct = 0; ct < 4; ++ct)
        bfr[ct] = *(bf16x8*)(lds + (ct * 16 + 8 + kk) * 1024 + lane * 16);
      __builtin_amdgcn_s_setprio(1);
#pragma unroll
      for (int ct = 0; ct < 4; ++ct)
        acc[ct] = __builtin_amdgcn_mfma_f32_32x32x16_bf16(af[kk], bfr[ct], acc[ct], 0, 0, 0);
      __builtin_amdgcn_s_setprio(0);
    }

    // gelu -> H (bf16 [32][128], swizzled). C layout: col=lane&31,
    // row=(reg&3)+8*(reg>>2)+4*lsel
#pragma unroll
    for (int ct = 0; ct < 4; ++ct)
#pragma unroll
      for (int reg = 0; reg < 16; ++reg) {
        int row = (reg & 3) + 8 * (reg >> 2) + 4 * lsel;
        int col = ct * 32 + l31;
        *(unsigned short*)(Hw + row * 256 + ((col * 2) ^ ((row & 7) << 4))) =
            bf1(gelu_f(acc[ct][reg]));
      }

    // GEMM2: K=128 (8 ksteps) from H; A frag: row=lane&31, k=kstep*16+lsel*8+j
    f32x16 acc2[4];
#pragma unroll
    for (int ct = 0; ct < 4; ++ct) {
      float b = bb1[ct];
#pragma unroll
      for (int q = 0; q < 16; ++q) acc2[ct][q] = b;
    }
    bf16x8 a2[8];
#pragma unroll
    for (int kk = 0; kk < 8; ++kk)
      a2[kk] = *(bf16x8*)(Hw + l31 * 256 +
                          ((kk * 32 + lsel * 16) ^ ((l31 & 7) << 4)));
#pragma unroll
    for (int kk = 0; kk < 8; ++kk) {
      bf16x8 bfr[4];
#pragma unroll
      for (int ct = 0; ct < 4; ++ct)
        bfr[ct] = *(bf16x8*)(lds + 65536 + (ct * 8 + kk) * 1024 + lane * 16);
      __builtin_amdgcn_s_setprio(1);
#pragma unroll
      for (int ct = 0; ct < 4; ++ct)
        acc2[ct] = __builtin_amdgcn_mfma_f32_32x32x16_bf16(a2[kk], bfr[ct], acc2[ct], 0, 0, 0);
      __builtin_amdgcn_s_setprio(0);
    }

    // gelu -> direct u16 global stores (32 consecutive cols per 32-lane half)
    const int row0 = t * 32;
#pragma unroll
    for (int ct = 0; ct < 4; ++ct)
#pragma unroll
      for (int reg = 0; reg < 16; ++reg) {
        int r = row0 + (reg & 3) + 8 * (reg >> 2) + 4 * lsel;
        if (r < E) {
          int col = ct * 32 + l31;
          hmsg[(size_t)r * 128 + col] = bf1(gelu_f(acc2[ct][reg]));
        }
      }
  }
}

// ---------------- aggregate (CSR gather) + LN1, wave per node ----------------
__global__ __launch_bounds__(256) void k_aggln(
    const unsigned* __restrict__ hmsg, const float2* __restrict__ hV,
    const int* __restrict__ row_start, const int* __restrict__ eorder,
    const float* __restrict__ g1, const float* __restrict__ be1,
    float2* __restrict__ hv1f, unsigned* __restrict__ hv1b, int Nn) {
  int wid = threadIdx.x >> 6, lane = threadIdx.x & 63;
  int node = blockIdx.x * 4 + wid;
  if (node >= Nn) return;
  int s = row_start[node], e = row_start[node + 1];
  float s0 = 0.f, s1 = 0.f;
  int i = s;
  for (; i + 3 < e; i += 4) {
    int e0 = eorder[i], e1 = eorder[i + 1], e2 = eorder[i + 2], e3 = eorder[i + 3];
    unsigned v0 = hmsg[(size_t)e0 * 64 + lane];
    unsigned v1 = hmsg[(size_t)e1 * 64 + lane];
    unsigned v2 = hmsg[(size_t)e2 * 64 + lane];
    unsigned v3 = hmsg[(size_t)e3 * 64 + lane];
    s0 += bf2f(v0 & 0xffffu) + bf2f(v1 & 0xffffu) + bf2f(v2 & 0xffffu) + bf2f(v3 & 0xffffu);
    s1 += bf2f(v0 >> 16) + bf2f(v1 >> 16) + bf2f(v2 >> 16) + bf2f(v3 >> 16);
  }
  for (; i < e; ++i) {
    unsigned v = hmsg[(size_t)eorder[i] * 64 + lane];
    s0 += bf2f(v & 0xffffu);
    s1 += bf2f(v >> 16);
  }
  float2 hv = hV[(size_t)node * 64 + lane];
  float x0 = hv.x + s0 * (1.f / 30.f);
  float x1 = hv.y + s1 * (1.f / 30.f);
  float sum = x0 + x1, sq = x0 * x0 + x1 * x1;
#pragma unroll
  for (int off = 32; off > 0; off >>= 1) {
    sum += __shfl_xor(sum, off);
    sq += __shfl_xor(sq, off);
  }
  float mu = sum * (1.f / 128.f);
  float var = sq * (1.f / 128.f) - mu * mu;
  float rs = rsqrtf(var + 1e-5f);
  int c = lane * 2;
  float y0 = (x0 - mu) * rs * g1[c] + be1[c];
  float y1 = (x1 - mu) * rs * g1[c + 1] + be1[c + 1];
  hv1f[(size_t)node * 64 + lane] = make_float2(y0, y1);
  hv1b[(size_t)node * 64 + lane] = (unsigned)pk2bf(y0, y1);
}

// ---------------- fused dense MLP: 3 GEMMs + residual + LN2, 32 rows/block ----------------
// LDS: A0 bf16[32][128]sw (8K) | D0 bf16[32][256]sw (16K, Y fp32 overlays) | D1 (16K)
__global__ __launch_bounds__(256, 4) void k_node(
    const unsigned short* __restrict__ xb, const unsigned short* __restrict__ pd0,
    const unsigned short* __restrict__ pd1, const unsigned short* __restrict__ pd2,
    const float* __restrict__ db0, const float* __restrict__ db1,
    const float* __restrict__ db2, const float* __restrict__ hv1f,
    const float* __restrict__ g2, const float* __restrict__ be2,
    float* __restrict__ out, int Nn) {
  __shared__ __align__(16) char lds[8192 + 16384 + 16384];
  char* A0 = lds;
  char* D0 = lds + 8192;
  char* D1 = lds + 8192 + 16384;
  float* Y = (float*)D0;
  const int tid = threadIdx.x, wid = tid >> 6, lane = tid & 63;
  const int l15 = lane & 15, lhi = lane >> 4;
  const int row0 = blockIdx.x * 32;

  // stage x (bf16 [32][128]) into A0, swizzled
  {
    int idx = tid;
    int r = idx >> 3, c = idx & 7;  // 32 rows x 8 uint4
    uint4 v = make_uint4(0u, 0u, 0u, 0u);
    if (row0 + r < Nn) v = ((const uint4*)xb)[(size_t)(row0 + r) * 16 + c * 2];
    *(uint4*)(A0 + r * 256 + ((c * 32) ^ ((r & 7) << 4))) = v;
    uint4 v2 = make_uint4(0u, 0u, 0u, 0u);
    if (row0 + r < Nn) v2 = ((const uint4*)xb)[(size_t)(row0 + r) * 16 + c * 2 + 1];
    *(uint4*)(A0 + r * 256 + (((c * 32) + 16) ^ ((r & 7) << 4))) = v2;
  }
  __syncthreads();

  // GEMM0: d0 = gelu(x @ W0 + b0), K=128, wave owns 64 of 256 cols
  {
    f32x4 acc[2][4];
#pragma unroll
    for (int ct = 0; ct < 4; ++ct) {
      float b = db0[wid * 64 + ct * 16 + l15];
#pragma unroll
      for (int mt = 0; mt < 2; ++mt) {
        acc[mt][ct][0] = b; acc[mt][ct][1] = b; acc[mt][ct][2] = b; acc[mt][ct][3] = b;
      }
    }
#pragma unroll
    for (int ks = 0; ks < 4; ++ks) {
      bf16x8 a[2];
#pragma unroll
      for (int mt = 0; mt < 2; ++mt) {
        int row = mt * 16 + l15;
        a[mt] = *(bf16x8*)(A0 + row * 256 + ((ks * 64 + lhi * 16) ^ ((row & 7) << 4)));
      }
#pragma unroll
      for (int ct = 0; ct < 4; ++ct) {
        uint4 bv = ((const uint4*)pd0)[(size_t)(wid * 16 + ct * 4 + ks) * 64 + lane];
        bf16x8 b = *(bf16x8*)&bv;
#pragma unroll
        for (int mt = 0; mt < 2; ++mt)
          acc[mt][ct] = __builtin_amdgcn_mfma_f32_16x16x32_bf16(a[mt], b, acc[mt][ct], 0, 0, 0);
      }
    }
#pragma unroll
    for (int ct = 0; ct < 4; ++ct) {
      int col = wid * 64 + ct * 16 + l15;
#pragma unroll
      for (int mt = 0; mt < 2; ++mt)
#pragma unroll
        for (int j = 0; j < 4; ++j) {
          int r = mt * 16 + lhi * 4 + j;
          *(unsigned short*)(D0 + r * 512 + ((col * 2) ^ ((r & 7) << 4))) =
              bf1(gelu_f(acc[mt][ct][j]));
        }
    }
  }
  __syncthreads();

  // GEMM1: d1 = gelu(d0 @ W1 + b1), K=256
  {
    f32x4 acc[2][4];
#pragma unroll
    for (int ct = 0; ct < 4; ++ct) {
      float b = db1[wid * 64 + ct * 16 + l15];
#pragma unroll
      for (int mt = 0; mt < 2; ++mt) {
        acc[mt][ct][0] = b; acc[mt][ct][1] = b; acc[mt][ct][2] = b; acc[mt][ct][3] = b;
      }
    }
#pragma unroll
    for (int ks = 0; ks < 8; ++ks) {
      bf16x8 a[2];
#pragma unroll
      for (int mt = 0; mt < 2; ++mt) {
        int row = mt * 16 + l15;
        a[mt] = *(bf16x8*)(D0 + row * 512 + ((ks * 64 + lhi * 16) ^ ((row & 7) << 4)));
      }
#pragma unroll
      for (int ct = 0; ct < 4; ++ct) {
        uint4 bv = ((const uint4*)pd1)[(size_t)(wid * 32 + ct * 8 + ks) * 64 + lane];
        bf16x8 b = *(bf16x8*)&bv;
#pragma unroll
        for (int mt = 0; mt < 2; ++mt)
          acc[mt][ct] = __builtin_amdgcn_mfma_f32_16x16x32_bf16(a[mt], b, acc[mt][ct], 0, 0, 0);
      }
    }
#pragma unroll
    for (int ct = 0; ct < 4; ++ct) {
      int col = wid * 64 + ct * 16 + l15;
#pragma unroll
      for (int mt = 0; mt < 2; ++mt)
#pragma unroll
        for (int j = 0; j < 4; ++j) {
          int r = mt * 16 + lhi * 4 + j;
          *(unsigned short*)(D1 + r * 512 + ((col * 2) ^ ((r & 7) << 4))) =
              bf1(gelu_f(acc[mt][ct][j]));
        }
    }
  }
  __syncthreads();

  // GEMM2: y = d1 @ W2 + b2 + residual, K=256, N=128; write fp32 Y (overlays D0)
  {
    f32x4 acc[2][2];
#pragma unroll
    for (int ct = 0; ct < 2; ++ct) {
      float b = db2[wid * 32 + ct * 16 + l15];
#pragma unroll
      for (int mt = 0; mt < 2; ++mt) {
        acc[mt][ct][0] = b; acc[mt][ct][1] = b; acc[mt][ct][2] = b; acc[mt][ct][3] = b;
      }
    }
#pragma unroll
    for (int ks = 0; ks < 8; ++ks) {
      bf16x8 a[2];
#pragma unroll
      for (int mt = 0; mt < 2; ++mt) {
        int row = mt * 16 + l15;
        a[mt] = *(bf16x8*)(D1 + row * 512 + ((ks * 64 + lhi * 16) ^ ((row & 7) << 4)));
      }
#pragma unroll
      for (int ct = 0; ct < 2; ++ct) {
        uint4 bv = ((const uint4*)pd2)[(size_t)(wid * 16 + ct * 8 + ks) * 64 + lane];
        bf16x8 b = *(bf16x8*)&bv;
#pragma unroll
        for (int mt = 0; mt < 2; ++mt)
          acc[mt][ct] = __builtin_amdgcn_mfma_f32_16x16x32_bf16(a[mt], b, acc[mt][ct], 0, 0, 0);
      }
    }
    __syncthreads();  // D0 reads done (GEMM1 passed); safe to overlay Y
#pragma unroll
    for (int ct = 0; ct < 2; ++ct) {
      int col = wid * 32 + ct * 16 + l15;
#pragma unroll
      for (int mt = 0; mt < 2; ++mt)
#pragma unroll
        for (int j = 0; j < 4; ++j) {
          int r = mt * 16 + lhi * 4 + j;
          int grow = row0 + r;
          float res = (grow < Nn) ? hv1f[(size_t)grow * 128 + col] : 0.f;
          Y[r * 128 + col] = acc[mt][ct][j] + res;
        }
    }
  }
  __syncthreads();

  // LN2 -> out (8 rows per wave)
  float g2a = g2[lane * 2], g2b = g2[lane * 2 + 1];
  float ba = be2[lane * 2], bbx = be2[lane * 2 + 1];
  for (int ii = 0; ii < 8; ++ii) {
    int r = wid * 8 + ii;
    int grow = row0 + r;
    if (grow >= Nn) continue;  // wave-uniform
    float2 xy = *(float2*)&Y[r * 128 + lane * 2];
    float sum = xy.x + xy.y, sq = xy.x * xy.x + xy.y * xy.y;
#pragma unroll
    for (int off = 32; off > 0; off >>= 1) {
      sum += __shfl_xor(sum, off);
      sq += __shfl_xor(sq, off);
    }
    float mu = sum * (1.f / 128.f);
    float var = sq * (1.f / 128.f) - mu * mu;
    float rs = rsqrtf(var + 1e-5f);
    float y0 = (xy.x - mu) * rs * g2a + ba;
    float y1 = (xy.y - mu) * rs * g2b + bbx;
    *(float2*)&out[(size_t)grow * 128 + lane * 2] = make_float2(y0, y1);
  }
}

// ---------------- host ----------------
extern "C" void kernel_launch(void* const* d_in, const int* in_sizes, int n_in,
                              void* d_out, int out_size, void* d_ws, size_t ws_size,
                              hipStream_t stream) {
  const float* hV  = (const float*)d_in[0];
  const float* hE  = (const float*)d_in[1];
  const int* eidx  = (const int*)d_in[2];
  const float* mw0 = (const float*)d_in[3];
  const float* mb0 = (const float*)d_in[4];
  const float* mw1 = (const float*)d_in[5];
  const float* mb1 = (const float*)d_in[6];
  const float* dw0 = (const float*)d_in[7];
  const float* db0 = (const float*)d_in[8];
  const float* dw1 = (const float*)d_in[9];
  const float* db1 = (const float*)d_in[10];
  const float* dw2 = (const float*)d_in[11];
  const float* db2 = (const float*)d_in[12];
  const float* g1  = (const float*)d_in[13];
  const float* be1 = (const float*)d_in[14];
  const float* g2  = (const float*)d_in[15];
  const float* be2 = (const float*)d_in[16];
  const int Nn = in_sizes[0] / 128;
  const int E  = in_sizes[1] / 256;

  char* ws = (char*)d_ws;
  size_t off = 0;
  auto alloc = [&](size_t bytes) -> char* {
    off = (off + 255) & ~(size_t)255;
    char* p = ws + off;
    off += bytes;
    return p;
  };
  unsigned short* hmsg = (unsigned short*)alloc((size_t)E * 128 * 2);
  float* hv1f          = (float*)alloc((size_t)Nn * 128 * 4);
  unsigned short* hv1b = (unsigned short*)alloc((size_t)Nn * 128 * 2);
  unsigned short* pw0  = (unsigned short*)alloc(32768 * 2);
  unsigned short* pw1  = (unsigned short*)alloc(16384 * 2);
  unsigned short* pd0  = (unsigned short*)alloc(32768 * 2);
  unsigned short* pd1  = (unsigned short*)alloc(65536 * 2);
  unsigned short* pd2  = (unsigned short*)alloc(32768 * 2);
  int* counts    = (int*)alloc((size_t)Nn * 4);
  int* row_start = (int*)alloc((size_t)(Nn + 1) * 4);
  int* cursor    = (int*)alloc((size_t)Nn * 4);
  int* eorder    = (int*)alloc((size_t)E * 4);

  k_pack<<<352, 64, 0, stream>>>(mw0, mw1, dw0, dw1, dw2, pw0, pw1, pd0, pd1, pd2,
                                 counts, Nn);
  k_hist<<<(E + 255) / 256, 256, 0, stream>>>(eidx, counts, E);
  k_scan<<<1, 1024, 0, stream>>>(counts, row_start, cursor, Nn);
  k_scatter<<<(E + 255) / 256, 256, 0, stream>>>(eidx, cursor, eorder, E);
  k_edge<<<256, 512, 0, stream>>>(hE, pw0, pw1, mb0, mb1, hmsg, E);
  k_aggln<<<(Nn + 3) / 4, 256, 0, stream>>>((const unsigned*)hmsg, (const float2*)hV,
                                            row_start, eorder, g1, be1,
                                            (float2*)hv1f, (unsigned*)hv1b, Nn);
  const int nt = (Nn + 31) / 32;
  k_node<<<nt, 256, 0, stream>>>(hv1b, pd0, pd1, pd2, db0, db1, db2,
                                 hv1f, g2, be2, (float*)d_out, Nn);
}

// Round 18
// 128.921 us; speedup vs baseline: 1.6311x; 1.6311x over previous
//
#include <hip/hip_runtime.h>
#include <hip/hip_bf16.h>

// MPNN layer: edge MLP (LDS weights, 16-row waves, prefetch + 4-deep batched
// ds_reads + setprio) -> CSR scatter-sum -> LN -> fused dense MLP + LN2.
// N=10000, E=160000, H=128, NIN=128, DD=256 (sizes derived at runtime).

typedef __attribute__((ext_vector_type(8))) short bf16x8;
typedef __attribute__((ext_vector_type(4))) float f32x4;

__device__ __forceinline__ unsigned short f2bf(float f) {
  union { float f; unsigned u; } v; v.f = f;
  return (unsigned short)((v.u + 0x7fffu + ((v.u >> 16) & 1u)) >> 16);
}
__device__ __forceinline__ unsigned pk2bf(float a, float b) {
  __hip_bfloat162 h = __float22bfloat162_rn(make_float2(a, b));  // v_cvt_pk_bf16_f32
  union { __hip_bfloat162 h; unsigned u; } v; v.h = h;
  return v.u;
}
// single bf16 via one cvt_pk op (RNE), low half
__device__ __forceinline__ unsigned short bf1(float x) {
  return (unsigned short)pk2bf(x, x);
}
__device__ __forceinline__ float bf2f(unsigned s) {
  union { unsigned u; float f; } v; v.u = s << 16;
  return v.f;
}
// gelu tanh-form, ~10 VALU ops, |err| <= ~3e-4 (inside bf16 granularity)
__device__ __forceinline__ float gelu_f(float x) {
  float x2 = x * x;
  float u2 = x * fmaf(0.0713548162f, x2, 1.5957691216f);  // 2*0.7978846*(x+0.044715x^3)
  float e = __expf(u2);                                    // e^{2u}
  float r = __builtin_amdgcn_rcpf(e + 1.0f);
  float th = fmaf(-2.0f, r, 1.0f);                         // tanh(u)
  float hx = 0.5f * x;
  return fmaf(hx, th, hx);
}

// ---------------- weight packing + counts zero + edge histogram ----------------
// blocks 0..351: pack weights into MFMA B-fragment order
//   b_frag[j] = B[k = ks*32 + (lane>>4)*8 + j][n = w*WC + ct*16 + (lane&15)]
//   group g = w*(CT*KS) + ct*KS + ks ; dst[(g*64+lane)*8 + j]
// blocks 352..735: histogram of edge src indices (eidx[0..E)) into counts
__global__ void k_pack(const float* __restrict__ mw0, const float* __restrict__ mw1,
                       const float* __restrict__ dw0, const float* __restrict__ dw1,
                       const float* __restrict__ dw2,
                       unsigned short* __restrict__ pw0, unsigned short* __restrict__ pw1,
                       unsigned short* __restrict__ pd0, unsigned short* __restrict__ pd1,
                       unsigned short* __restrict__ pd2,
                       int* __restrict__ counts, int Nn,
                       const int* __restrict__ eidx, int E) {
  int g = blockIdx.x, lane = threadIdx.x;
  int z = g * 64 + lane;
  if (z < Nn) counts[z] = 0;
  if (g >= 352) {
    // histogram part: 384 blocks x 64 threads, grid-stride over E
    int base = (g - 352) * 64 + lane;
    for (int e = base; e < E; e += 384 * 64) atomicAdd(&counts[eidx[e]], 1);
    return;
  }
  const float* src; unsigned short* dst; int K, N, WC, base;
  if (g < 64)       { src = mw0; dst = pw0; K = 256; N = 128; WC = 128; base = 0; }
  else if (g < 96)  { src = mw1; dst = pw1; K = 128; N = 128; WC = 128; base = 64; }
  else if (g < 160) { src = dw0; dst = pd0; K = 128; N = 256; WC = 64; base = 96; }
  else if (g < 288) { src = dw1; dst = pd1; K = 256; N = 256; WC = 64; base = 160; }
  else              { src = dw2; dst = pd2; K = 256; N = 128; WC = 32; base = 288; }
  int lg = g - base;
  int KS = K >> 5, CTKS = (WC >> 4) * KS;
  int w = lg / CTKS, rem = lg % CTKS, ct = rem / KS, ks = rem % KS;
  int col = w * WC + ct * 16 + (lane & 15);
  int k0 = ks * 32 + (lane >> 4) * 8;
  unsigned short o[8];
#pragma unroll
  for (int j = 0; j < 8; ++j) o[j] = f2bf(src[(size_t)(k0 + j) * N + col]);
  uint4 u;
  u.x = (unsigned)o[0] | ((unsigned)o[1] << 16);
  u.y = (unsigned)o[2] | ((unsigned)o[3] << 16);
  u.z = (unsigned)o[4] | ((unsigned)o[5] << 16);
  u.w = (unsigned)o[6] | ((unsigned)o[7] << 16);
  *(uint4*)(dst + (size_t)(lg * 64 + lane) * 8) = u;
}

// NOTE: k_pack's histogram part must see counts zeroed by the SAME kernel's
// earlier writes — different blocks may race. Zeroing is done by blocks 0..157
// (z<Nn) while histogram blocks are 352..735: no ordering guarantee. To stay
// safe, counts zeroing stays in k_pack (all blocks write disjoint z) and the
// histogram is a separate kernel below.
__global__ void k_hist(const int* __restrict__ eidx, int* __restrict__ counts, int E) {
  int e = blockIdx.x * 256 + threadIdx.x;
  if (e < E) atomicAdd(&counts[eidx[e]], 1);
}

__global__ __launch_bounds__(1024) void k_scan(const int* __restrict__ counts,
                                               int* __restrict__ row_start,
                                               int* __restrict__ cursor, int Nn) {
  __shared__ int sm[1024];
  int t = threadIdx.x;
  int chunk = (Nn + 1023) / 1024;
  int lo = t * chunk, hi = lo + chunk;
  if (hi > Nn) hi = Nn;
  int s = 0;
  for (int i = lo; i < hi; ++i) s += counts[i];
  sm[t] = s;
  __syncthreads();
  for (int o = 1; o < 1024; o <<= 1) {
    int u = (t >= o) ? sm[t - o] : 0;
    __syncthreads();
    sm[t] += u;
    __syncthreads();
  }
  int run = sm[t] - s;  // exclusive prefix
  for (int i = lo; i < hi; ++i) {
    row_start[i] = run; cursor[i] = run; run += counts[i];
  }
  if (t == 1023) row_start[Nn] = sm[1023];
}

__global__ void k_scatter(const int* __restrict__ eidx, int* __restrict__ cursor,
                          int* __restrict__ eorder, int E) {
  int e = blockIdx.x * 256 + threadIdx.x;
  if (e < E) {
    int pos = atomicAdd(&cursor[eidx[e]], 1);
    eorder[pos] = e;
  }
}

// ---------------- fused edge MLP: h_msg = gelu(gelu(hE@W0+b0)@W1+b1) ----------------
// 256 persistent blocks x 8 waves, __launch_bounds__(512,2). LDS = 128KB:
// 64K W0 | 32K W1 | 8 x 4K H. Wave owns 16 rows x 128 cols, barrier-free:
// A prefetched 1 tile ahead in regs; B fragments ds_read in 4-deep batches;
// setprio(1) around MFMA clusters; wave-private H slice; direct u16 stores.
__global__ __launch_bounds__(512, 2) void k_edge(
    const float* __restrict__ hE, const unsigned short* __restrict__ pw0,
    const unsigned short* __restrict__ pw1, const float* __restrict__ b0,
    const float* __restrict__ b1, unsigned short* __restrict__ hmsg, int E) {
  __shared__ __align__(16) char lds[131072];  // 64K W0 | 32K W1 | 8 x 4K H slices
  const int tid = threadIdx.x;                // 0..511
  const int wid = tid >> 6, lane = tid & 63;
  const int l15 = lane & 15, lhi = lane >> 4;
  char* Hw = lds + 98304 + wid * 4096;

  // stage weights: 96 KB = 6144 uint4 (512 threads x 12)
  {
    const uint4* s0 = (const uint4*)pw0;  // 4096 uint4
    const uint4* s1 = (const uint4*)pw1;  // 2048 uint4
    uint4* d = (uint4*)lds;
#pragma unroll
    for (int i = 0; i < 12; ++i) {
      int idx = i * 512 + tid;
      d[idx] = (idx < 4096) ? s0[idx] : s1[idx - 4096];
    }
  }
  float bb0[8], bb1[8];
#pragma unroll
  for (int ct = 0; ct < 8; ++ct) {
    bb0[ct] = b0[ct * 16 + l15];
    bb1[ct] = b1[ct * 16 + l15];
  }
  __syncthreads();  // weights visible to all waves; no barriers after this

  const int TILES = (E + 15) >> 4;
  const int WSLOTS = gridDim.x * 8;
  int t = blockIdx.x * 8 + wid;
  if (t >= TILES) return;

  // prefetch first tile: row = l15, cols lhi*8 + ks*32 + {0..7}
  f32x4 av[16];
  {
    int rowA = t * 16 + l15; rowA = rowA < E ? rowA : E - 1;
    const float* ap = hE + (size_t)rowA * 256 + lhi * 8;
#pragma unroll
    for (int ks = 0; ks < 8; ++ks) {
      av[2 * ks]     = *(const f32x4*)(ap + ks * 32);
      av[2 * ks + 1] = *(const f32x4*)(ap + ks * 32 + 4);
    }
  }

  for (; t < TILES; t += WSLOTS) {
    const int tn = t + WSLOTS;
    // convert current tile to bf16 A-fragments (frees av for next prefetch)
    bf16x8 af[8];
#pragma unroll
    for (int ks = 0; ks < 8; ++ks) {
      union { unsigned u[4]; bf16x8 v; } pk;
      pk.u[0] = pk2bf(av[2 * ks][0], av[2 * ks][1]);
      pk.u[1] = pk2bf(av[2 * ks][2], av[2 * ks][3]);
      pk.u[2] = pk2bf(av[2 * ks + 1][0], av[2 * ks + 1][1]);
      pk.u[3] = pk2bf(av[2 * ks + 1][2], av[2 * ks + 1][3]);
      af[ks] = pk.v;
    }
    // prefetch next tile (in flight across GEMM1+GEMM2)
    if (tn < TILES) {
      int rowA = tn * 16 + l15; rowA = rowA < E ? rowA : E - 1;
      const float* ap = hE + (size_t)rowA * 256 + lhi * 8;
#pragma unroll
      for (int ks = 0; ks < 8; ++ks) {
        av[2 * ks]     = *(const f32x4*)(ap + ks * 32);
        av[2 * ks + 1] = *(const f32x4*)(ap + ks * 32 + 4);
      }
    }

    // GEMM1: K=256; B fragments batched 4-deep; acc initialized with bias b0
    f32x4 acc[8];
#pragma unroll
    for (int ct = 0; ct < 8; ++ct) {
      float b = bb0[ct];
      acc[ct][0] = b; acc[ct][1] = b; acc[ct][2] = b; acc[ct][3] = b;
    }
#pragma unroll
    for (int ks = 0; ks < 8; ++ks) {
#pragma unroll
      for (int g = 0; g < 2; ++g) {
        bf16x8 bfr[4];
#pragma unroll
        for (int q = 0; q < 4; ++q)
          bfr[q] = *(bf16x8*)(lds + ((g * 4 + q) * 8 + ks) * 1024 + lane * 16);
        __builtin_amdgcn_s_setprio(1);
#pragma unroll
        for (int q = 0; q < 4; ++q)
          acc[g * 4 + q] =
              __builtin_amdgcn_mfma_f32_16x16x32_bf16(af[ks], bfr[q], acc[g * 4 + q], 0, 0, 0);
        __builtin_amdgcn_s_setprio(0);
      }
    }
    // gelu -> H (bf16 [16][128], swizzled), wave-private
#pragma unroll
    for (int ct = 0; ct < 8; ++ct)
#pragma unroll
      for (int j = 0; j < 4; ++j) {
        int r = lhi * 4 + j, col = ct * 16 + l15;
        *(unsigned short*)(Hw + r * 256 + ((col * 2) ^ ((r & 7) << 4))) =
            bf1(gelu_f(acc[ct][j]));
      }

    // GEMM2: K=128 from H; B fragments batched 4-deep; acc2 init with bias b1
    f32x4 acc2[8];
#pragma unroll
    for (int ct = 0; ct < 8; ++ct) {
      float b = bb1[ct];
      acc2[ct][0] = b; acc2[ct][1] = b; acc2[ct][2] = b; acc2[ct][3] = b;
    }
#pragma unroll
    for (int ks = 0; ks < 4; ++ks) {
      bf16x8 a = *(bf16x8*)(Hw + l15 * 256 + ((ks * 64 + lhi * 16) ^ ((l15 & 7) << 4)));
#pragma unroll
      for (int g = 0; g < 2; ++g) {
        bf16x8 bfr[4];
#pragma unroll
        for (int q = 0; q < 4; ++q)
          bfr[q] = *(bf16x8*)(lds + 65536 + ((g * 4 + q) * 4 + ks) * 1024 + lane * 16);
        __builtin_amdgcn_s_setprio(1);
#pragma unroll
        for (int q = 0; q < 4; ++q)
          acc2[g * 4 + q] =
              __builtin_amdgcn_mfma_f32_16x16x32_bf16(a, bfr[q], acc2[g * 4 + q], 0, 0, 0);
        __builtin_amdgcn_s_setprio(0);
      }
    }
    // gelu -> direct u16 global stores; wave-uniform full-tile fast path
    const int row0 = t * 16;
    if (row0 + 16 <= E) {
#pragma unroll
      for (int ct = 0; ct < 8; ++ct)
#pragma unroll
        for (int j = 0; j < 4; ++j) {
          int r = row0 + lhi * 4 + j;
          int col = ct * 16 + l15;
          hmsg[(size_t)r * 128 + col] = bf1(gelu_f(acc2[ct][j]));
        }
    } else {
#pragma unroll
      for (int ct = 0; ct < 8; ++ct)
#pragma unroll
        for (int j = 0; j < 4; ++j) {
          int r = row0 + lhi * 4 + j;
          if (r < E) {
            int col = ct * 16 + l15;
            hmsg[(size_t)r * 128 + col] = bf1(gelu_f(acc2[ct][j]));
          }
        }
    }
  }
}

// ---------------- aggregate (CSR gather) + LN1, wave per node ----------------
__global__ __launch_bounds__(256) void k_aggln(
    const unsigned* __restrict__ hmsg, const float2* __restrict__ hV,
    const int* __restrict__ row_start, const int* __restrict__ eorder,
    const float* __restrict__ g1, const float* __restrict__ be1,
    float2* __restrict__ hv1f, unsigned* __restrict__ hv1b, int Nn) {
  int wid = threadIdx.x >> 6, lane = threadIdx.x & 63;
  int node = blockIdx.x * 4 + wid;
  if (node >= Nn) return;
  int s = row_start[node], e = row_start[node + 1];
  float s0 = 0.f, s1 = 0.f;
  int i = s;
  for (; i + 3 < e; i += 4) {
    int e0 = eorder[i], e1 = eorder[i + 1], e2 = eorder[i + 2], e3 = eorder[i + 3];
    unsigned v0 = hmsg[(size_t)e0 * 64 + lane];
    unsigned v1 = hmsg[(size_t)e1 * 64 + lane];
    unsigned v2 = hmsg[(size_t)e2 * 64 + lane];
    unsigned v3 = hmsg[(size_t)e3 * 64 + lane];
    s0 += bf2f(v0 & 0xffffu) + bf2f(v1 & 0xffffu) + bf2f(v2 & 0xffffu) + bf2f(v3 & 0xffffu);
    s1 += bf2f(v0 >> 16) + bf2f(v1 >> 16) + bf2f(v2 >> 16) + bf2f(v3 >> 16);
  }
  for (; i < e; ++i) {
    unsigned v = hmsg[(size_t)eorder[i] * 64 + lane];
    s0 += bf2f(v & 0xffffu);
    s1 += bf2f(v >> 16);
  }
  float2 hv = hV[(size_t)node * 64 + lane];
  float x0 = hv.x + s0 * (1.f / 30.f);
  float x1 = hv.y + s1 * (1.f / 30.f);
  float sum = x0 + x1, sq = x0 * x0 + x1 * x1;
#pragma unroll
  for (int off = 32; off > 0; off >>= 1) {
    sum += __shfl_xor(sum, off);
    sq += __shfl_xor(sq, off);
  }
  float mu = sum * (1.f / 128.f);
  float var = sq * (1.f / 128.f) - mu * mu;
  float rs = rsqrtf(var + 1e-5f);
  int c = lane * 2;
  float y0 = (x0 - mu) * rs * g1[c] + be1[c];
  float y1 = (x1 - mu) * rs * g1[c + 1] + be1[c + 1];
  hv1f[(size_t)node * 64 + lane] = make_float2(y0, y1);
  hv1b[(size_t)node * 64 + lane] = (unsigned)pk2bf(y0, y1);
}

// ---------------- fused dense MLP: 3 GEMMs + residual + LN2, 32 rows/block ----------------
// LDS: A0 bf16[32][128]sw (8K) | D0 bf16[32][256]sw (16K, Y fp32 overlays) | D1 (16K)
__global__ __launch_bounds__(256, 4) void k_node(
    const unsigned short* __restrict__ xb, const unsigned short* __restrict__ pd0,
    const unsigned short* __restrict__ pd1, const unsigned short* __restrict__ pd2,
    const float* __restrict__ db0, const float* __restrict__ db1,
    const float* __restrict__ db2, const float* __restrict__ hv1f,
    const float* __restrict__ g2, const float* __restrict__ be2,
    float* __restrict__ out, int Nn) {
  __shared__ __align__(16) char lds[8192 + 16384 + 16384];
  char* A0 = lds;
  char* D0 = lds + 8192;
  char* D1 = lds + 8192 + 16384;
  float* Y = (float*)D0;
  const int tid = threadIdx.x, wid = tid >> 6, lane = tid & 63;
  const int l15 = lane & 15, lhi = lane >> 4;
  const int row0 = blockIdx.x * 32;

  // stage x (bf16 [32][128]) into A0, swizzled
  {
    int idx = tid;
    int r = idx >> 3, c = idx & 7;  // 32 rows x 8 uint4
    uint4 v = make_uint4(0u, 0u, 0u, 0u);
    if (row0 + r < Nn) v = ((const uint4*)xb)[(size_t)(row0 + r) * 16 + c * 2];
    *(uint4*)(A0 + r * 256 + ((c * 32) ^ ((r & 7) << 4))) = v;
    uint4 v2 = make_uint4(0u, 0u, 0u, 0u);
    if (row0 + r < Nn) v2 = ((const uint4*)xb)[(size_t)(row0 + r) * 16 + c * 2 + 1];
    *(uint4*)(A0 + r * 256 + (((c * 32) + 16) ^ ((r & 7) << 4))) = v2;
  }
  __syncthreads();

  // GEMM0: d0 = gelu(x @ W0 + b0), K=128, wave owns 64 of 256 cols
  {
    f32x4 acc[2][4];
#pragma unroll
    for (int ct = 0; ct < 4; ++ct) {
      float b = db0[wid * 64 + ct * 16 + l15];
#pragma unroll
      for (int mt = 0; mt < 2; ++mt) {
        acc[mt][ct][0] = b; acc[mt][ct][1] = b; acc[mt][ct][2] = b; acc[mt][ct][3] = b;
      }
    }
#pragma unroll
    for (int ks = 0; ks < 4; ++ks) {
      bf16x8 a[2];
#pragma unroll
      for (int mt = 0; mt < 2; ++mt) {
        int row = mt * 16 + l15;
        a[mt] = *(bf16x8*)(A0 + row * 256 + ((ks * 64 + lhi * 16) ^ ((row & 7) << 4)));
      }
#pragma unroll
      for (int ct = 0; ct < 4; ++ct) {
        uint4 bv = ((const uint4*)pd0)[(size_t)(wid * 16 + ct * 4 + ks) * 64 + lane];
        bf16x8 b = *(bf16x8*)&bv;
#pragma unroll
        for (int mt = 0; mt < 2; ++mt)
          acc[mt][ct] = __builtin_amdgcn_mfma_f32_16x16x32_bf16(a[mt], b, acc[mt][ct], 0, 0, 0);
      }
    }
#pragma unroll
    for (int ct = 0; ct < 4; ++ct) {
      int col = wid * 64 + ct * 16 + l15;
#pragma unroll
      for (int mt = 0; mt < 2; ++mt)
#pragma unroll
        for (int j = 0; j < 4; ++j) {
          int r = mt * 16 + lhi * 4 + j;
          *(unsigned short*)(D0 + r * 512 + ((col * 2) ^ ((r & 7) << 4))) =
              bf1(gelu_f(acc[mt][ct][j]));
        }
    }
  }
  __syncthreads();

  // GEMM1: d1 = gelu(d0 @ W1 + b1), K=256
  {
    f32x4 acc[2][4];
#pragma unroll
    for (int ct = 0; ct < 4; ++ct) {
      float b = db1[wid * 64 + ct * 16 + l15];
#pragma unroll
      for (int mt = 0; mt < 2; ++mt) {
        acc[mt][ct][0] = b; acc[mt][ct][1] = b; acc[mt][ct][2] = b; acc[mt][ct][3] = b;
      }
    }
#pragma unroll
    for (int ks = 0; ks < 8; ++ks) {
      bf16x8 a[2];
#pragma unroll
      for (int mt = 0; mt < 2; ++mt) {
        int row = mt * 16 + l15;
        a[mt] = *(bf16x8*)(D0 + row * 512 + ((ks * 64 + lhi * 16) ^ ((row & 7) << 4)));
      }
#pragma unroll
      for (int ct = 0; ct < 4; ++ct) {
        uint4 bv = ((const uint4*)pd1)[(size_t)(wid * 32 + ct * 8 + ks) * 64 + lane];
        bf16x8 b = *(bf16x8*)&bv;
#pragma unroll
        for (int mt = 0; mt < 2; ++mt)
          acc[mt][ct] = __builtin_amdgcn_mfma_f32_16x16x32_bf16(a[mt], b, acc[mt][ct], 0, 0, 0);
      }
    }
#pragma unroll
    for (int ct = 0; ct < 4; ++ct) {
      int col = wid * 64 + ct * 16 + l15;
#pragma unroll
      for (int mt = 0; mt < 2; ++mt)
#pragma unroll
        for (int j = 0; j < 4; ++j) {
          int r = mt * 16 + lhi * 4 + j;
          *(unsigned short*)(D1 + r * 512 + ((col * 2) ^ ((r & 7) << 4))) =
              bf1(gelu_f(acc[mt][ct][j]));
        }
    }
  }
  __syncthreads();

  // GEMM2: y = d1 @ W2 + b2 + residual, K=256, N=128; write fp32 Y (overlays D0)
  {
    f32x4 acc[2][2];
#pragma unroll
    for (int ct = 0; ct < 2; ++ct) {
      float b = db2[wid * 32 + ct * 16 + l15];
#pragma unroll
      for (int mt = 0; mt < 2; ++mt) {
        acc[mt][ct][0] = b; acc[mt][ct][1] = b; acc[mt][ct][2] = b; acc[mt][ct][3] = b;
      }
    }
#pragma unroll
    for (int ks = 0; ks < 8; ++ks) {
      bf16x8 a[2];
#pragma unroll
      for (int mt = 0; mt < 2; ++mt) {
        int row = mt * 16 + l15;
        a[mt] = *(bf16x8*)(D1 + row * 512 + ((ks * 64 + lhi * 16) ^ ((row & 7) << 4)));
      }
#pragma unroll
      for (int ct = 0; ct < 2; ++ct) {
        uint4 bv = ((const uint4*)pd2)[(size_t)(wid * 16 + ct * 8 + ks) * 64 + lane];
        bf16x8 b = *(bf16x8*)&bv;
#pragma unroll
        for (int mt = 0; mt < 2; ++mt)
          acc[mt][ct] = __builtin_amdgcn_mfma_f32_16x16x32_bf16(a[mt], b, acc[mt][ct], 0, 0, 0);
      }
    }
    __syncthreads();  // D0 reads done (GEMM1 passed); safe to overlay Y
#pragma unroll
    for (int ct = 0; ct < 2; ++ct) {
      int col = wid * 32 + ct * 16 + l15;
#pragma unroll
      for (int mt = 0; mt < 2; ++mt)
#pragma unroll
        for (int j = 0; j < 4; ++j) {
          int r = mt * 16 + lhi * 4 + j;
          int grow = row0 + r;
          float res = (grow < Nn) ? hv1f[(size_t)grow * 128 + col] : 0.f;
          Y[r * 128 + col] = acc[mt][ct][j] + res;
        }
    }
  }
  __syncthreads();

  // LN2 -> out (8 rows per wave)
  float g2a = g2[lane * 2], g2b = g2[lane * 2 + 1];
  float ba = be2[lane * 2], bbx = be2[lane * 2 + 1];
  for (int ii = 0; ii < 8; ++ii) {
    int r = wid * 8 + ii;
    int grow = row0 + r;
    if (grow >= Nn) continue;  // wave-uniform
    float2 xy = *(float2*)&Y[r * 128 + lane * 2];
    float sum = xy.x + xy.y, sq = xy.x * xy.x + xy.y * xy.y;
#pragma unroll
    for (int off = 32; off > 0; off >>= 1) {
      sum += __shfl_xor(sum, off);
      sq += __shfl_xor(sq, off);
    }
    float mu = sum * (1.f / 128.f);
    float var = sq * (1.f / 128.f) - mu * mu;
    float rs = rsqrtf(var + 1e-5f);
    float y0 = (xy.x - mu) * rs * g2a + ba;
    float y1 = (xy.y - mu) * rs * g2b + bbx;
    *(float2*)&out[(size_t)grow * 128 + lane * 2] = make_float2(y0, y1);
  }
}

// ---------------- host ----------------
extern "C" void kernel_launch(void* const* d_in, const int* in_sizes, int n_in,
                              void* d_out, int out_size, void* d_ws, size_t ws_size,
                              hipStream_t stream) {
  const float* hV  = (const float*)d_in[0];
  const float* hE  = (const float*)d_in[1];
  const int* eidx  = (const int*)d_in[2];
  const float* mw0 = (const float*)d_in[3];
  const float* mb0 = (const float*)d_in[4];
  const float* mw1 = (const float*)d_in[5];
  const float* mb1 = (const float*)d_in[6];
  const float* dw0 = (const float*)d_in[7];
  const float* db0 = (const float*)d_in[8];
  const float* dw1 = (const float*)d_in[9];
  const float* db1 = (const float*)d_in[10];
  const float* dw2 = (const float*)d_in[11];
  const float* db2 = (const float*)d_in[12];
  const float* g1  = (const float*)d_in[13];
  const float* be1 = (const float*)d_in[14];
  const float* g2  = (const float*)d_in[15];
  const float* be2 = (const float*)d_in[16];
  const int Nn = in_sizes[0] / 128;
  const int E  = in_sizes[1] / 256;

  char* ws = (char*)d_ws;
  size_t off = 0;
  auto alloc = [&](size_t bytes) -> char* {
    off = (off + 255) & ~(size_t)255;
    char* p = ws + off;
    off += bytes;
    return p;
  };
  unsigned short* hmsg = (unsigned short*)alloc((size_t)E * 128 * 2);
  float* hv1f          = (float*)alloc((size_t)Nn * 128 * 4);
  unsigned short* hv1b = (unsigned short*)alloc((size_t)Nn * 128 * 2);
  unsigned short* pw0  = (unsigned short*)alloc(32768 * 2);
  unsigned short* pw1  = (unsigned short*)alloc(16384 * 2);
  unsigned short* pd0  = (unsigned short*)alloc(32768 * 2);
  unsigned short* pd1  = (unsigned short*)alloc(65536 * 2);
  unsigned short* pd2  = (unsigned short*)alloc(32768 * 2);
  int* counts    = (int*)alloc((size_t)Nn * 4);
  int* row_start = (int*)alloc((size_t)(Nn + 1) * 4);
  int* cursor    = (int*)alloc((size_t)Nn * 4);
  int* eorder    = (int*)alloc((size_t)E * 4);

  k_pack<<<352, 64, 0, stream>>>(mw0, mw1, dw0, dw1, dw2, pw0, pw1, pd0, pd1, pd2,
                                 counts, Nn, eidx, E);
  k_hist<<<(E + 255) / 256, 256, 0, stream>>>(eidx, counts, E);
  k_scan<<<1, 1024, 0, stream>>>(counts, row_start, cursor, Nn);
  k_scatter<<<(E + 255) / 256, 256, 0, stream>>>(eidx, cursor, eorder, E);
  k_edge<<<256, 512, 0, stream>>>(hE, pw0, pw1, mb0, mb1, hmsg, E);
  k_aggln<<<(Nn + 3) / 4, 256, 0, stream>>>((const unsigned*)hmsg, (const float2*)hV,
                                            row_start, eorder, g1, be1,
                                            (float2*)hv1f, (unsigned*)hv1b, Nn);
  const int nt = (Nn + 31) / 32;
  k_node<<<nt, 256, 0, stream>>>(hv1b, pd0, pd1, pd2, db0, db1, db2,
                                 hv1f, g2, be2, (float*)d_out, Nn);
}